// Round 15
// baseline (175.985 us; speedup 1.0000x reference)
//
#include <hip/hip_runtime.h>

// MultiheadAttentionWithBias: B=2, L=2048, D=1024, H=16, HD=64
// R15 = R14 (bias-dedup batch-merged blocks) with the vmcnt(0) drain bubble
// removed: 32-k panels, TRIPLE-buffered LDS (96KB), counted vmcnt(4) with
// depth-2 prefetch -- the stage pipe never drains in the main loop (T4).

typedef __attribute__((ext_vector_type(8))) short bf16x8;
typedef __attribute__((ext_vector_type(4))) float f32x4;
typedef __attribute__((ext_vector_type(16))) float f32x16;
typedef __attribute__((ext_vector_type(8))) unsigned short u16x8;
using u16 = unsigned short;

#define MFMA16(a, b, c) __builtin_amdgcn_mfma_f32_16x16x32_bf16((a), (b), (c), 0, 0, 0)
#define MFMA32(a, b, c) __builtin_amdgcn_mfma_f32_32x32x16_bf16((a), (b), (c), 0, 0, 0)
#define LOG2E 1.44269504088896f
#define QSCALE (0.125f * 1.44269504088896f)

__device__ __forceinline__ u16 f2bf(float f) {
  union { float f; unsigned int u; } v; v.f = f;
  unsigned int r = v.u + 0x7FFFu + ((v.u >> 16) & 1u);
  return (u16)(r >> 16);
}

__device__ __forceinline__ unsigned cvt_pk_bf16(float lo, float hi) {
  unsigned r;
  asm volatile("v_cvt_pk_bf16_f32 %0, %1, %2" : "=v"(r) : "v"(lo), "v"(hi));
  return r;
}

__device__ __forceinline__ void pl32swap(unsigned& a, unsigned& b) {
#if __has_builtin(__builtin_amdgcn_permlane32_swap)
  typedef unsigned pl2 __attribute__((ext_vector_type(2)));
  pl2 r = __builtin_amdgcn_permlane32_swap(a, b, false, false);
  a = r[0];
  b = r[1];
#else
  asm volatile("v_permlane32_swap_b32 %0, %1" : "+v"(a), "+v"(b));
#endif
}

__device__ __forceinline__ void g2lds16(const void* gsrc, void* ldst) {
  __builtin_amdgcn_global_load_lds(
      (const __attribute__((address_space(1))) unsigned int*)gsrc,
      (__attribute__((address_space(3))) unsigned int*)ldst, 16, 0, 0);
}

// ---------------- merged f32 -> bf16 convert (x, Wq, Wk, Wv, Wo) ----------------
__global__ __launch_bounds__(256) void cvt_all(
    const float* __restrict__ x, const float* __restrict__ wq,
    const float* __restrict__ wk, const float* __restrict__ wv,
    const float* __restrict__ wo, u16* __restrict__ xb,
    u16* __restrict__ w1b, u16* __restrict__ wob) {
  int bid = blockIdx.x, tid = threadIdx.x;
  const float* src; u16* dst; int i;
  if (bid < 2048)      { src = x;  dst = xb;            i = bid * 256 + tid; }
  else if (bid < 2560) { src = wq; dst = w1b;           i = (bid - 2048) * 256 + tid; }
  else if (bid < 3072) { src = wk; dst = w1b + (1<<20); i = (bid - 2560) * 256 + tid; }
  else if (bid < 3584) { src = wv; dst = w1b + (2<<20); i = (bid - 3072) * 256 + tid; }
  else                 { src = wo; dst = wob;           i = (bid - 3584) * 256 + tid; }
  const float4* s = (const float4*)src;
  float4 a = s[2 * i], b = s[2 * i + 1];
  u16x8 o;
  o[0] = f2bf(a.x); o[1] = f2bf(a.y); o[2] = f2bf(a.z); o[3] = f2bf(a.w);
  o[4] = f2bf(b.x); o[5] = f2bf(b.y); o[6] = f2bf(b.z); o[7] = f2bf(b.w);
  ((u16x8*)dst)[i] = o;
}

// ---------------- GEMM C = A * B^T (unchanged, passing) ----------------
template <int MODE>
__global__ __launch_bounds__(256, 2) void gemm_bt(
    const u16* __restrict__ A, const u16* __restrict__ B,
    u16* __restrict__ qp, u16* __restrict__ kp, u16* __restrict__ vp,
    const float* __restrict__ b0, const float* __restrict__ b1,
    const float* __restrict__ b2, float* __restrict__ outp,
    const float* __restrict__ bo) {
  __shared__ __align__(16) u16 lA[128 * 64];
  __shared__ __align__(16) u16 lB[128 * 64];
  const int tid = threadIdx.x;
  const int lane = tid & 63, wid = tid >> 6;
  const int g = lane >> 4, cc = lane & 15;
  const int wr = wid >> 1, wc = wid & 1;
  const int m0 = blockIdx.y * 128, n0 = blockIdx.x * 128;
  f32x4 acc[4][4] = {};
  for (int kt = 0; kt < 16; ++kt) {
    const int kof = kt * 64;
#pragma unroll
    for (int i = 0; i < 4; ++i) {
      int cid = i * 256 + tid;
      int row = cid >> 3;
      int col = (cid & 7) * 8;
      g2lds16(A + (size_t)(m0 + row) * 1024 + kof + col, &lA[(i * 256 + wid * 64) * 8]);
      g2lds16(B + (size_t)(n0 + row) * 1024 + kof + col, &lB[(i * 256 + wid * 64) * 8]);
    }
    __syncthreads();
#pragma unroll
    for (int kc = 0; kc < 2; ++kc) {
      bf16x8 af[4], bfr[4];
#pragma unroll
      for (int mf = 0; mf < 4; ++mf)
        af[mf] = *(const bf16x8*)&lA[(wr * 64 + mf * 16 + cc) * 64 + kc * 32 + g * 8];
#pragma unroll
      for (int nf = 0; nf < 4; ++nf)
        bfr[nf] = *(const bf16x8*)&lB[(wc * 64 + nf * 16 + cc) * 64 + kc * 32 + g * 8];
#pragma unroll
      for (int mf = 0; mf < 4; ++mf)
#pragma unroll
        for (int nf = 0; nf < 4; ++nf)
          acc[mf][nf] = MFMA16(af[mf], bfr[nf], acc[mf][nf]);
    }
    __syncthreads();
  }
#pragma unroll
  for (int mf = 0; mf < 4; ++mf) {
#pragma unroll
    for (int nf = 0; nf < 4; ++nf) {
      int n = n0 + wc * 64 + nf * 16 + cc;
      if (MODE == 0) {
        int which = n >> 10;
        int nn = n & 1023;
        const float* bp = which == 0 ? b0 : (which == 1 ? b1 : b2);
        float bias = bp[nn];
        int h = nn >> 6, hd = nn & 63;
        int mb = m0 + wr * 64 + mf * 16 + g * 4;
        int bb = mb >> 11, ll0 = mb & 2047;
        if (which == 2) {
          ushort4 pk4;
          pk4.x = f2bf(acc[mf][nf][0] + bias);
          pk4.y = f2bf(acc[mf][nf][1] + bias);
          pk4.z = f2bf(acc[mf][nf][2] + bias);
          pk4.w = f2bf(acc[mf][nf][3] + bias);
          *(ushort4*)&vp[(((size_t)(bb * 16 + h)) * 64 + hd) * 2048 + ll0] = pk4;
        } else {
          u16* dp = which == 0 ? qp : kp;
#pragma unroll
          for (int r = 0; r < 4; ++r) {
            float val = acc[mf][nf][r] + bias;
            if (which == 0) val *= QSCALE;
            dp[(((size_t)(bb * 16 + h)) * 2048 + ll0 + r) * 64 + hd] = f2bf(val);
          }
        }
      } else {
        float bias = bo[n];
#pragma unroll
        for (int r = 0; r < 4; ++r) {
          int m = m0 + wr * 64 + mf * 16 + g * 4 + r;
          outp[(size_t)m * 1024 + n] = acc[mf][nf][r] + bias;
        }
      }
    }
  }
}

// ---------------- Flash attention: bias-dedup + counted-vmcnt pipeline --------
// Grid 256 = 16h x 16qb (q-block 128 rows). Block 512 thr = 8 waves =
// 2 batches x 4 q-strips. 64 panels of 32 k. Per panel staged (4 g2lds/thread):
//   bias[128q x 32k] f32 16KB (read ONCE, both batch-waves consume),
//   K[2b][32k][64d] 8KB, V^T[2b][64d][32k] 8KB  -> 32KB/panel, 3 bufs = 96KB.
// Pipeline (T4): iter p = vmcnt(4) [stage(p) done, stage(p+1) in flight]
//   -> s_barrier -> issue stage(p+2) -> compute(p). NEVER drains to 0 in loop.
// Fixed-max(-32) in-register softmax core (R12/R14 refcheck-passed).
__global__ __launch_bounds__(512, 1) void attn_kernel(
    const u16* __restrict__ qm, const u16* __restrict__ km,
    const u16* __restrict__ vtm, const float* __restrict__ bias,
    u16* __restrict__ aout) {
  __shared__ __align__(16) unsigned char smem[98304];  // 3 bufs x 32KB
  // per buf: bias 16KB @0, K 8KB @16384, V 8KB @24576
  const int tid = threadIdx.x;
  const int lane = tid & 63, wid = tid >> 6;
  const int lq = lane & 31, hi = lane >> 5;
  const int s = wid & 3, b = wid >> 2;     // q-strip, batch
  // XCD swizzle: 256 blocks; xcd = lin&7 owns heads 2*xcd, 2*xcd+1
  const int lin = blockIdx.x;
  const int xcd = lin & 7, j = lin >> 3;   // j in [0,32)
  const int h = xcd * 2 + (j >> 4);
  const int qb = j & 15;
  const int q0 = qb * 128;
  const u16* kg0 = km + ((size_t)0 * 16 + h) * 2048 * 64;
  const u16* kg1 = km + ((size_t)1 * 16 + h) * 2048 * 64;
  const u16* vg0 = vtm + ((size_t)0 * 16 + h) * 64 * 2048;
  const u16* vg1 = vtm + ((size_t)1 * 16 + h) * 64 * 2048;
  const float* bg = bias + (size_t)h * 2048 * 2048;
  const size_t bh = (size_t)b * 16 + h;
  const u16* qbase = qm + (bh * 2048 + q0 + s * 32) * 64;

  // Q fragments (B-operand), constant: Q[q=lq][d=i*16+8hi..]
  bf16x8 qf[4];
#pragma unroll
  for (int i = 0; i < 4; ++i)
    qf[i] = *(const bf16x8*)&qbase[(size_t)lq * 64 + i * 16 + 8 * hi];

  f32x16 o[2];
#pragma unroll
  for (int r = 0; r < 16; ++r) { o[0][r] = 0.f; o[1][r] = 0.f; }
  float lsum = 0.f;

  // Stage one 32-k panel into buf BI. All XOR swizzles pre-applied on the
  // SOURCE (T2 both-sides, linear LDS dst). 4 g2lds per thread.
#define STAGE_P(BI, k0n)                                                       \
  {                                                                            \
    unsigned char* base = smem + (BI) * 32768;                                 \
    unsigned char* kdst = base + 16384;                                        \
    unsigned char* vdst = base + 24576;                                        \
    _Pragma("unroll") for (int i = 0; i < 2; ++i) {                            \
      int slot = i * 512 + tid;                                                \
      int row = slot >> 3, ch = slot & 7;                                      \
      g2lds16(bg + (size_t)(q0 + row) * 2048 + (k0n) + ((ch ^ (row & 7)) << 2),\
              base + slot * 16);                                               \
    }                                                                          \
    {                                                                          \
      int bb = tid >> 8, kr = (tid >> 3) & 31, ch = tid & 7;                   \
      const u16* kgp = bb ? kg1 : kg0;                                         \
      g2lds16(kgp + (size_t)((k0n) + kr) * 64 + ((ch ^ (kr & 7)) << 3),        \
              kdst + tid * 16);                                                \
    }                                                                          \
    {                                                                          \
      int bb = tid >> 8, d = (tid >> 2) & 63, ch = tid & 3;                    \
      const u16* vgp = bb ? vg1 : vg0;                                         \
      g2lds16(vgp + (size_t)d * 2048 + (k0n) + ((ch ^ (d & 3)) << 3),          \
              vdst + tid * 16);                                                \
    }                                                                          \
  }

  // prologue: stage panels 0,1 -> bufs 0,1 (8 ops in flight)
  STAGE_P(0, 0)
  STAGE_P(1, 32)
  __builtin_amdgcn_sched_barrier(0);

#pragma unroll 1
  for (int p = 0; p < 64; ++p) {
    const int BI = p % 3;
    // stage(p) done; stage(p+1) stays in flight (4 newest ops)
    if (p < 63) { asm volatile("s_waitcnt vmcnt(4)" ::: "memory"); }
    else        { asm volatile("s_waitcnt vmcnt(0)" ::: "memory"); }
    __builtin_amdgcn_sched_barrier(0);
    __builtin_amdgcn_s_barrier();  // all waves' stage(p) landed; buf (p+2)%3 free
    __builtin_amdgcn_sched_barrier(0);
    if (p + 2 < 64) { STAGE_P((p + 2) % 3, (p + 2) * 32) }
    __builtin_amdgcn_sched_barrier(0);
    // ---- compute panel p from buf BI ----
    const u16* lKp = (const u16*)(smem + BI * 32768 + 16384 + b * 4096);
    const u16* lVp = (const u16*)(smem + BI * 32768 + 24576 + b * 4096);
    const float4* lB = (const float4*)(smem + BI * 32768);
    f32x16 acc;
#pragma unroll
    for (int r = 0; r < 16; ++r) acc[r] = -32.0f;  // fixed-max fold
#pragma unroll
    for (int i = 0; i < 4; ++i) {
      bf16x8 kf = *(const bf16x8*)&lKp[lq * 64 + (((2 * i + hi) ^ (lq & 7))) * 8];
      acc = MFMA32(kf, qf[i], acc);
    }
    const int brow = s * 32 + lq;
#pragma unroll
    for (int g = 0; g < 4; ++g) {
      float4 b4 = lB[brow * 8 + ((2 * g + hi) ^ (brow & 7))];
      acc[g * 4 + 0] = fmaf(b4.x, LOG2E, acc[g * 4 + 0]);
      acc[g * 4 + 1] = fmaf(b4.y, LOG2E, acc[g * 4 + 1]);
      acc[g * 4 + 2] = fmaf(b4.z, LOG2E, acc[g * 4 + 2]);
      acc[g * 4 + 3] = fmaf(b4.w, LOG2E, acc[g * 4 + 3]);
    }
#pragma unroll
    for (int r = 0; r < 16; ++r) {
      acc[r] = __builtin_amdgcn_exp2f(acc[r]);
      lsum += acc[r];
    }
    unsigned c0 = cvt_pk_bf16(acc[0], acc[1]),   c1 = cvt_pk_bf16(acc[2], acc[3]);
    unsigned c2 = cvt_pk_bf16(acc[4], acc[5]),   c3 = cvt_pk_bf16(acc[6], acc[7]);
    unsigned c4 = cvt_pk_bf16(acc[8], acc[9]),   c5 = cvt_pk_bf16(acc[10], acc[11]);
    unsigned c6 = cvt_pk_bf16(acc[12], acc[13]), c7 = cvt_pk_bf16(acc[14], acc[15]);
    pl32swap(c0, c2); pl32swap(c1, c3);
    pl32swap(c4, c6); pl32swap(c5, c7);
    union { unsigned u[4]; bf16x8 v; } a0, a1;
    a0.u[0] = c0; a0.u[1] = c1; a0.u[2] = c2; a0.u[3] = c3;
    a1.u[0] = c4; a1.u[1] = c5; a1.u[2] = c6; a1.u[3] = c7;
#pragma unroll
    for (int dblk = 0; dblk < 2; ++dblk) {
      int rowv = dblk * 32 + lq;
      bf16x8 v0 = *(const bf16x8*)&lVp[rowv * 32 + ((hi ^ (rowv & 3))) * 8];
      bf16x8 v1 = *(const bf16x8*)&lVp[rowv * 32 + (((2 + hi) ^ (rowv & 3))) * 8];
      o[dblk] = MFMA32(a0.v, v0, o[dblk]);
      o[dblk] = MFMA32(a1.v, v1, o[dblk]);
    }
    __builtin_amdgcn_sched_barrier(0);
  }
#undef STAGE_P

  // epilogue: each wave owns distinct (b, q-strip) -> direct write, no combine
  lsum += __shfl_xor(lsum, 32, 64);
  float linv = 1.0f / lsum;
#pragma unroll
  for (int r = 0; r < 16; ++r) {
    int qr = (r & 3) + 8 * (r >> 2) + 4 * hi;
    float lr = __shfl(linv, qr, 64);
    size_t base = ((size_t)b * 2048 + q0 + s * 32 + qr) * 1024 + h * 64 + lq;
    aout[base] = f2bf(o[0][r] * lr);
    aout[base + 32] = f2bf(o[1][r] * lr);
  }
}

extern "C" void kernel_launch(void* const* d_in, const int* in_sizes, int n_in,
                              void* d_out, int out_size, void* d_ws, size_t ws_size,
                              hipStream_t stream) {
  const float* x  = (const float*)d_in[0];
  const float* rb = (const float*)d_in[1];
  const float* Wq = (const float*)d_in[2];
  const float* bq = (const float*)d_in[3];
  const float* Wk = (const float*)d_in[4];
  const float* bk = (const float*)d_in[5];
  const float* Wv = (const float*)d_in[6];
  const float* bv = (const float*)d_in[7];
  const float* Wo = (const float*)d_in[8];
  const float* bo = (const float*)d_in[9];
  float* out = (float*)d_out;
  char* ws = (char*)d_ws;

  u16* xb   = (u16*)(ws);                 // 8 MB  [4096,1024] bf16 (reused as aout)
  u16* W1b  = (u16*)(ws + (8 << 20));     // 6 MB  [3072,1024] bf16 (Wq|Wk|Wv)
  u16* Wob  = (u16*)(ws + (14 << 20));    // 2 MB  [1024,1024] bf16
  u16* qb   = (u16*)(ws + (16 << 20));    // 8 MB  [B,H,L,HD]
  u16* kb2  = (u16*)(ws + (24 << 20));    // 8 MB  [B,H,L,HD]
  u16* vtb  = (u16*)(ws + (32 << 20));    // 8 MB  [B,H,HD,L] (written by QKV GEMM)
  u16* aout = xb;                         // alias: xb dead after QKV GEMM

  cvt_all<<<4096, 256, 0, stream>>>(x, Wq, Wk, Wv, Wo, xb, W1b, Wob);
  gemm_bt<0><<<dim3(24, 32), 256, 0, stream>>>(xb, W1b, qb, kb2, vtb, bq, bk, bv,
                                               nullptr, nullptr);
  attn_kernel<<<256, 512, 0, stream>>>(qb, kb2, vtb, rb, aout);
  gemm_bt<1><<<dim3(8, 32), 256, 0, stream>>>(aout, Wob, nullptr, nullptr, nullptr,
                                              nullptr, nullptr, nullptr, out, bo);
}

// Round 16
// 157.558 us; speedup vs baseline: 1.1170x; 1.1170x over previous
//
#include <hip/hip_runtime.h>

// MultiheadAttentionWithBias: B=2, L=2048, D=1024, H=16, HD=64
// R16: decisive staging-path test. R15's verified 32-k-panel layout/core, but
// staging is REG-BASED (T14/HK): global_load_dwordx4 -> regs (issued one full
// iteration early) -> vmcnt(0) -> ds_write_b128 -> barrier. Decouples VMEM
// issue from the LDS-write-coupled global_load_lds retirement path.
// Dbuf 64KB LDS. Bias still staged ONCE per (h,q,k) (R14 dedup).

typedef __attribute__((ext_vector_type(8))) short bf16x8;
typedef __attribute__((ext_vector_type(4))) float f32x4;
typedef __attribute__((ext_vector_type(16))) float f32x16;
typedef __attribute__((ext_vector_type(8))) unsigned short u16x8;
using u16 = unsigned short;

#define MFMA16(a, b, c) __builtin_amdgcn_mfma_f32_16x16x32_bf16((a), (b), (c), 0, 0, 0)
#define MFMA32(a, b, c) __builtin_amdgcn_mfma_f32_32x32x16_bf16((a), (b), (c), 0, 0, 0)
#define LOG2E 1.44269504088896f
#define QSCALE (0.125f * 1.44269504088896f)

__device__ __forceinline__ u16 f2bf(float f) {
  union { float f; unsigned int u; } v; v.f = f;
  unsigned int r = v.u + 0x7FFFu + ((v.u >> 16) & 1u);
  return (u16)(r >> 16);
}

__device__ __forceinline__ unsigned cvt_pk_bf16(float lo, float hi) {
  unsigned r;
  asm volatile("v_cvt_pk_bf16_f32 %0, %1, %2" : "=v"(r) : "v"(lo), "v"(hi));
  return r;
}

__device__ __forceinline__ void pl32swap(unsigned& a, unsigned& b) {
#if __has_builtin(__builtin_amdgcn_permlane32_swap)
  typedef unsigned pl2 __attribute__((ext_vector_type(2)));
  pl2 r = __builtin_amdgcn_permlane32_swap(a, b, false, false);
  a = r[0];
  b = r[1];
#else
  asm volatile("v_permlane32_swap_b32 %0, %1" : "+v"(a), "+v"(b));
#endif
}

__device__ __forceinline__ void g2lds16(const void* gsrc, void* ldst) {
  __builtin_amdgcn_global_load_lds(
      (const __attribute__((address_space(1))) unsigned int*)gsrc,
      (__attribute__((address_space(3))) unsigned int*)ldst, 16, 0, 0);
}

// ---------------- merged f32 -> bf16 convert (x, Wq, Wk, Wv, Wo) ----------------
__global__ __launch_bounds__(256) void cvt_all(
    const float* __restrict__ x, const float* __restrict__ wq,
    const float* __restrict__ wk, const float* __restrict__ wv,
    const float* __restrict__ wo, u16* __restrict__ xb,
    u16* __restrict__ w1b, u16* __restrict__ wob) {
  int bid = blockIdx.x, tid = threadIdx.x;
  const float* src; u16* dst; int i;
  if (bid < 2048)      { src = x;  dst = xb;            i = bid * 256 + tid; }
  else if (bid < 2560) { src = wq; dst = w1b;           i = (bid - 2048) * 256 + tid; }
  else if (bid < 3072) { src = wk; dst = w1b + (1<<20); i = (bid - 2560) * 256 + tid; }
  else if (bid < 3584) { src = wv; dst = w1b + (2<<20); i = (bid - 3072) * 256 + tid; }
  else                 { src = wo; dst = wob;           i = (bid - 3584) * 256 + tid; }
  const float4* s = (const float4*)src;
  float4 a = s[2 * i], b = s[2 * i + 1];
  u16x8 o;
  o[0] = f2bf(a.x); o[1] = f2bf(a.y); o[2] = f2bf(a.z); o[3] = f2bf(a.w);
  o[4] = f2bf(b.x); o[5] = f2bf(b.y); o[6] = f2bf(b.z); o[7] = f2bf(b.w);
  ((u16x8*)dst)[i] = o;
}

// ---------------- GEMM C = A * B^T (unchanged, passing) ----------------
template <int MODE>
__global__ __launch_bounds__(256, 2) void gemm_bt(
    const u16* __restrict__ A, const u16* __restrict__ B,
    u16* __restrict__ qp, u16* __restrict__ kp, u16* __restrict__ vp,
    const float* __restrict__ b0, const float* __restrict__ b1,
    const float* __restrict__ b2, float* __restrict__ outp,
    const float* __restrict__ bo) {
  __shared__ __align__(16) u16 lA[128 * 64];
  __shared__ __align__(16) u16 lB[128 * 64];
  const int tid = threadIdx.x;
  const int lane = tid & 63, wid = tid >> 6;
  const int g = lane >> 4, cc = lane & 15;
  const int wr = wid >> 1, wc = wid & 1;
  const int m0 = blockIdx.y * 128, n0 = blockIdx.x * 128;
  f32x4 acc[4][4] = {};
  for (int kt = 0; kt < 16; ++kt) {
    const int kof = kt * 64;
#pragma unroll
    for (int i = 0; i < 4; ++i) {
      int cid = i * 256 + tid;
      int row = cid >> 3;
      int col = (cid & 7) * 8;
      g2lds16(A + (size_t)(m0 + row) * 1024 + kof + col, &lA[(i * 256 + wid * 64) * 8]);
      g2lds16(B + (size_t)(n0 + row) * 1024 + kof + col, &lB[(i * 256 + wid * 64) * 8]);
    }
    __syncthreads();
#pragma unroll
    for (int kc = 0; kc < 2; ++kc) {
      bf16x8 af[4], bfr[4];
#pragma unroll
      for (int mf = 0; mf < 4; ++mf)
        af[mf] = *(const bf16x8*)&lA[(wr * 64 + mf * 16 + cc) * 64 + kc * 32 + g * 8];
#pragma unroll
      for (int nf = 0; nf < 4; ++nf)
        bfr[nf] = *(const bf16x8*)&lB[(wc * 64 + nf * 16 + cc) * 64 + kc * 32 + g * 8];
#pragma unroll
      for (int mf = 0; mf < 4; ++mf)
#pragma unroll
        for (int nf = 0; nf < 4; ++nf)
          acc[mf][nf] = MFMA16(af[mf], bfr[nf], acc[mf][nf]);
    }
    __syncthreads();
  }
#pragma unroll
  for (int mf = 0; mf < 4; ++mf) {
#pragma unroll
    for (int nf = 0; nf < 4; ++nf) {
      int n = n0 + wc * 64 + nf * 16 + cc;
      if (MODE == 0) {
        int which = n >> 10;
        int nn = n & 1023;
        const float* bp = which == 0 ? b0 : (which == 1 ? b1 : b2);
        float bias = bp[nn];
        int h = nn >> 6, hd = nn & 63;
        int mb = m0 + wr * 64 + mf * 16 + g * 4;
        int bb = mb >> 11, ll0 = mb & 2047;
        if (which == 2) {
          ushort4 pk4;
          pk4.x = f2bf(acc[mf][nf][0] + bias);
          pk4.y = f2bf(acc[mf][nf][1] + bias);
          pk4.z = f2bf(acc[mf][nf][2] + bias);
          pk4.w = f2bf(acc[mf][nf][3] + bias);
          *(ushort4*)&vp[(((size_t)(bb * 16 + h)) * 64 + hd) * 2048 + ll0] = pk4;
        } else {
          u16* dp = which == 0 ? qp : kp;
#pragma unroll
          for (int r = 0; r < 4; ++r) {
            float val = acc[mf][nf][r] + bias;
            if (which == 0) val *= QSCALE;
            dp[(((size_t)(bb * 16 + h)) * 2048 + ll0 + r) * 64 + hd] = f2bf(val);
          }
        }
      } else {
        float bias = bo[n];
#pragma unroll
        for (int r = 0; r < 4; ++r) {
          int m = m0 + wr * 64 + mf * 16 + g * 4 + r;
          outp[(size_t)m * 1024 + n] = acc[mf][nf][r] + bias;
        }
      }
    }
  }
}

// ---------------- Flash attention: reg-staged pipeline (T14) -------------------
// Grid 256 = 16h x 16qb (q-block 128 rows). Block 512 thr = 8 waves =
// 2 batches x 4 q-strips. 64 panels of 32 k. Per panel, per thread:
//   4x global_load_dwordx4 -> regs (issued ONE FULL ITERATION early)
//   ... compute(p) [zero VMEM] ... vmcnt(0) -> 4x ds_write_b128 -> barrier.
// LDS: 2 bufs x 32KB (bias16 + K8 + V8). Bias staged once (R14 dedup).
// Fixed-max(-32) in-register softmax core (R15 refcheck-passed, verbatim).
__global__ __launch_bounds__(512, 2) void attn_kernel(
    const u16* __restrict__ qm, const u16* __restrict__ km,
    const u16* __restrict__ vtm, const float* __restrict__ bias,
    u16* __restrict__ aout) {
  __shared__ __align__(16) unsigned char smem[65536];  // 2 bufs x 32KB
  // per buf: bias 16KB @0, K 8KB @16384, V 8KB @24576
  const int tid = threadIdx.x;
  const int lane = tid & 63, wid = tid >> 6;
  const int lq = lane & 31, hi = lane >> 5;
  const int s = wid & 3, b = wid >> 2;     // q-strip, batch
  // XCD swizzle: 256 blocks; xcd = lin&7 owns heads 2*xcd, 2*xcd+1
  const int lin = blockIdx.x;
  const int xcd = lin & 7, j = lin >> 3;   // j in [0,32)
  const int h = xcd * 2 + (j >> 4);
  const int qb = j & 15;
  const int q0 = qb * 128;
  const float* bg = bias + (size_t)h * 2048 * 2048;
  const size_t bh = (size_t)b * 16 + h;
  const u16* qbase = qm + (bh * 2048 + q0 + s * 32) * 64;

  // ---- per-thread stage source pointers (advance by constant stride/panel) ----
  // bias slots: slot_a = tid (rows 0..63), slot_b = 512+tid (rows 64..127)
  const int brow_a = tid >> 3, bch = tid & 7;
  const float* bsrcA = bg + (size_t)(q0 + brow_a) * 2048 + ((bch ^ (brow_a & 7)) << 2);
  const float* bsrcB = bg + (size_t)(q0 + 64 + brow_a) * 2048 + ((bch ^ ((64 + brow_a) & 7)) << 2);
  // K: bb = tid>>8, row kr = (tid>>3)&31, chunk ch = tid&7
  {
  }
  const int kbb = tid >> 8, kr = (tid >> 3) & 31, kch = tid & 7;
  const u16* ksrc = km + ((size_t)kbb * 16 + h) * 2048 * 64 + (size_t)kr * 64 +
                    ((kch ^ (kr & 7)) << 3);
  // V: bb = tid>>8, row d = (tid>>2)&63, chunk ch = tid&3
  const int vbb = tid >> 8, vd = (tid >> 2) & 63, vch = tid & 3;
  const u16* vsrc = vtm + ((size_t)vbb * 16 + h) * 64 * 2048 + (size_t)vd * 2048 +
                    ((vch ^ (vd & 3)) << 3);
  // linear LDS dst offsets (thread-const; add buf base at write time)
  const int dA = tid * 16, dB = (512 + tid) * 16;
  const int dK = 16384 + tid * 16, dV = 24576 + tid * 16;

  // Q fragments (B-operand), constant: Q[q=lq][d=i*16+8hi..]
  bf16x8 qf[4];
#pragma unroll
  for (int i = 0; i < 4; ++i)
    qf[i] = *(const bf16x8*)&qbase[(size_t)lq * 64 + i * 16 + 8 * hi];

  f32x16 o[2];
#pragma unroll
  for (int r = 0; r < 16; ++r) { o[0][r] = 0.f; o[1][r] = 0.f; }
  float lsum = 0.f;

  float4 rA, rB, rK, rV;  // stage registers (panel in flight)

#define ISSUE_LOADS()                                                          \
  {                                                                            \
    rA = *(const float4*)bsrcA;                                                \
    rB = *(const float4*)bsrcB;                                                \
    rK = *(const float4*)ksrc;                                                 \
    rV = *(const float4*)vsrc;                                                 \
    bsrcA += 32; bsrcB += 32; ksrc += 32 * 64; vsrc += 32;                     \
  }

#define WRITE_LDS(BI)                                                          \
  {                                                                            \
    unsigned char* base_ = smem + (BI) * 32768;                                \
    *(float4*)(base_ + dA) = rA;                                               \
    *(float4*)(base_ + dB) = rB;                                               \
    *(float4*)(base_ + dK) = rK;                                               \
    *(float4*)(base_ + dV) = rV;                                               \
  }

  // prologue: load(0) -> write buf0 -> issue load(1) -> barrier
  ISSUE_LOADS()
  __builtin_amdgcn_sched_barrier(0);
  asm volatile("s_waitcnt vmcnt(0)" ::: "memory");
  __builtin_amdgcn_sched_barrier(0);
  WRITE_LDS(0)
  ISSUE_LOADS()
  __builtin_amdgcn_sched_barrier(0);
  __syncthreads();

#pragma unroll 1
  for (int p = 0; p < 64; ++p) {
    const int BI = p & 1;
    // ---- compute panel p from buf BI (zero VMEM; loads(p+1) in flight) ----
    {
      const u16* lKp = (const u16*)(smem + BI * 32768 + 16384 + b * 4096);
      const u16* lVp = (const u16*)(smem + BI * 32768 + 24576 + b * 4096);
      const float4* lB = (const float4*)(smem + BI * 32768);
      f32x16 acc;
#pragma unroll
      for (int r = 0; r < 16; ++r) acc[r] = -32.0f;  // fixed-max fold
#pragma unroll
      for (int i = 0; i < 4; ++i) {
        bf16x8 kf = *(const bf16x8*)&lKp[lq * 64 + (((2 * i + hi) ^ (lq & 7))) * 8];
        acc = MFMA32(kf, qf[i], acc);
      }
      const int brow = s * 32 + lq;
#pragma unroll
      for (int g = 0; g < 4; ++g) {
        float4 b4 = lB[brow * 8 + ((2 * g + hi) ^ (brow & 7))];
        acc[g * 4 + 0] = fmaf(b4.x, LOG2E, acc[g * 4 + 0]);
        acc[g * 4 + 1] = fmaf(b4.y, LOG2E, acc[g * 4 + 1]);
        acc[g * 4 + 2] = fmaf(b4.z, LOG2E, acc[g * 4 + 2]);
        acc[g * 4 + 3] = fmaf(b4.w, LOG2E, acc[g * 4 + 3]);
      }
#pragma unroll
      for (int r = 0; r < 16; ++r) {
        acc[r] = __builtin_amdgcn_exp2f(acc[r]);
        lsum += acc[r];
      }
      unsigned c0 = cvt_pk_bf16(acc[0], acc[1]),   c1 = cvt_pk_bf16(acc[2], acc[3]);
      unsigned c2 = cvt_pk_bf16(acc[4], acc[5]),   c3 = cvt_pk_bf16(acc[6], acc[7]);
      unsigned c4 = cvt_pk_bf16(acc[8], acc[9]),   c5 = cvt_pk_bf16(acc[10], acc[11]);
      unsigned c6 = cvt_pk_bf16(acc[12], acc[13]), c7 = cvt_pk_bf16(acc[14], acc[15]);
      pl32swap(c0, c2); pl32swap(c1, c3);
      pl32swap(c4, c6); pl32swap(c5, c7);
      union { unsigned u[4]; bf16x8 v; } a0, a1;
      a0.u[0] = c0; a0.u[1] = c1; a0.u[2] = c2; a0.u[3] = c3;
      a1.u[0] = c4; a1.u[1] = c5; a1.u[2] = c6; a1.u[3] = c7;
#pragma unroll
      for (int dblk = 0; dblk < 2; ++dblk) {
        int rowv = dblk * 32 + lq;
        bf16x8 v0 = *(const bf16x8*)&lVp[rowv * 32 + ((hi ^ (rowv & 3))) * 8];
        bf16x8 v1 = *(const bf16x8*)&lVp[rowv * 32 + (((2 + hi) ^ (rowv & 3))) * 8];
        o[dblk] = MFMA32(a0.v, v0, o[dblk]);
        o[dblk] = MFMA32(a1.v, v1, o[dblk]);
      }
    }
    // ---- hand off panel p+1: regs -> LDS buf BI^1; issue loads(p+2) ----
    if (p < 63) {
      __builtin_amdgcn_sched_barrier(0);
      asm volatile("s_waitcnt vmcnt(0)" ::: "memory");  // loads(p+1) landed
      __builtin_amdgcn_sched_barrier(0);
      WRITE_LDS(BI ^ 1)
      __builtin_amdgcn_sched_barrier(0);
      if (p < 62) { ISSUE_LOADS() }
      __builtin_amdgcn_sched_barrier(0);
      __syncthreads();  // writes visible; all waves done reading buf BI
    }
  }
#undef WRITE_LDS
#undef ISSUE_LOADS

  // epilogue: each wave owns distinct (b, q-strip) -> direct write, no combine
  lsum += __shfl_xor(lsum, 32, 64);
  float linv = 1.0f / lsum;
#pragma unroll
  for (int r = 0; r < 16; ++r) {
    int qr = (r & 3) + 8 * (r >> 2) + 4 * hi;
    float lr = __shfl(linv, qr, 64);
    size_t base = ((size_t)b * 2048 + q0 + s * 32 + qr) * 1024 + h * 64 + lq;
    aout[base] = f2bf(o[0][r] * lr);
    aout[base + 32] = f2bf(o[1][r] * lr);
  }
}

extern "C" void kernel_launch(void* const* d_in, const int* in_sizes, int n_in,
                              void* d_out, int out_size, void* d_ws, size_t ws_size,
                              hipStream_t stream) {
  const float* x  = (const float*)d_in[0];
  const float* rb = (const float*)d_in[1];
  const float* Wq = (const float*)d_in[2];
  const float* bq = (const float*)d_in[3];
  const float* Wk = (const float*)d_in[4];
  const float* bk = (const float*)d_in[5];
  const float* Wv = (const float*)d_in[6];
  const float* bv = (const float*)d_in[7];
  const float* Wo = (const float*)d_in[8];
  const float* bo = (const float*)d_in[9];
  float* out = (float*)d_out;
  char* ws = (char*)d_ws;

  u16* xb   = (u16*)(ws);                 // 8 MB  [4096,1024] bf16 (reused as aout)
  u16* W1b  = (u16*)(ws + (8 << 20));     // 6 MB  [3072,1024] bf16 (Wq|Wk|Wv)
  u16* Wob  = (u16*)(ws + (14 << 20));    // 2 MB  [1024,1024] bf16
  u16* qb   = (u16*)(ws + (16 << 20));    // 8 MB  [B,H,L,HD]
  u16* kb2  = (u16*)(ws + (24 << 20));    // 8 MB  [B,H,L,HD]
  u16* vtb  = (u16*)(ws + (32 << 20));    // 8 MB  [B,H,HD,L] (written by QKV GEMM)
  u16* aout = xb;                         // alias: xb dead after QKV GEMM

  cvt_all<<<4096, 256, 0, stream>>>(x, Wq, Wk, Wv, Wo, xb, W1b, Wob);
  gemm_bt<0><<<dim3(24, 32), 256, 0, stream>>>(xb, W1b, qb, kb2, vtb, bq, bk, bv,
                                               nullptr, nullptr);
  attn_kernel<<<256, 512, 0, stream>>>(qb, kb2, vtb, rb, aout);
  gemm_bt<1><<<dim3(8, 32), 256, 0, stream>>>(aout, Wob, nullptr, nullptr, nullptr,
                                              nullptr, nullptr, nullptr, out, bo);
}